// Round 1
// baseline (922.022 us; speedup 1.0000x reference)
//
#include <hip/hip_runtime.h>
#include <math.h>

#define B_    32
#define H_    32
#define D_    128
#define KVH_  8
#define G_    4
#define P_    2048
#define T_    64
#define PPS_  64
#define NCHUNK 8
#define CHUNK_PAGES 8          // 512 tokens per chunk
#define RS4   33               // LDS row stride in float4 (132 floats; 132%32==4 -> balanced banks)

// ---------------- Kernel 1: per-(b, kv-head, chunk) flash-decode partial ----------------
__global__ __launch_bounds__(256, 2)
void pa_partial(const float* __restrict__ q,
                const float* __restrict__ k_pages,
                const float* __restrict__ v_pages,
                const int*   __restrict__ lengths,
                const int*   __restrict__ page_indices,
                float* __restrict__ o_part,   // [2048][G*D]
                float* __restrict__ m_part,   // [2048][G]
                float* __restrict__ l_part)   // [2048][G]
{
    __shared__ float4 K4[T_ * RS4];      // 33792 B
    __shared__ float4 V4[T_ * RS4];      // 33792 B
    __shared__ float4 q4s[G_ * 32];      // 2 KiB
    __shared__ float  p_s[G_ * T_];      // 1 KiB
    __shared__ float  alpha_s[G_];

    const int tid = threadIdx.x;
    const int bx  = blockIdx.x;
    const int c   = bx & (NCHUNK - 1);
    const int k   = (bx >> 3) & (KVH_ - 1);
    const int b   = bx >> 6;

    const int len = lengths[b];
    const int chunk_tok0 = c * (CHUNK_PAGES * T_);
    if (chunk_tok0 >= len) return;                 // uniform early exit

    const int nP = (len + T_ - 1) / T_;
    const int p0 = c * CHUNK_PAGES;
    const int p1 = min(nP, p0 + CHUNK_PAGES);

    // stage q[b, k*G .. k*G+3, :] (512 floats)
    {
        const float* qg = q + ((size_t)b * H_ + (size_t)k * G_) * D_;
        ((float*)q4s)[tid]       = qg[tid];
        ((float*)q4s)[tid + 256] = qg[tid + 256];
    }

    // score-phase mapping: wave = head g, lane = token t
    const int g = tid >> 6;
    const int t = tid & 63;
    float m_run = -INFINITY;
    float l_run = 0.f;

    // PV-phase mapping: dq = float4 column (4 d's), th = token octet
    const int dq = tid & 31;
    const int th = tid >> 5;
    float4 oacc[G_];
#pragma unroll
    for (int i = 0; i < G_; ++i) { oacc[i].x = 0.f; oacc[i].y = 0.f; oacc[i].z = 0.f; oacc[i].w = 0.f; }

    __syncthreads();   // q4s visible

    for (int p = p0; p < p1; ++p) {
        const int page = page_indices[b * PPS_ + p];
        const float4* Kg = (const float4*)(k_pages + ((size_t)k * P_ + (size_t)page) * (T_ * D_));
        const float4* Vg = (const float4*)(v_pages + ((size_t)k * P_ + (size_t)page) * (T_ * D_));

        // ---- stage K,V page -> LDS (coalesced, bank-balanced layout) ----
#pragma unroll
        for (int i = 0; i < 8; ++i) {
            const int f  = tid + 256 * i;
            const int tt = f >> 5;
            const int jj = f & 31;
            K4[tt * RS4 + jj] = Kg[f];
            V4[tt * RS4 + jj] = Vg[f];
        }
        __syncthreads();

        // ---- scores: thread (g, t) dot over D=128 ----
        float s = 0.f;
        {
            const float4* Kr = &K4[t * RS4];
            const float4* qr = &q4s[g * 32];
#pragma unroll
            for (int i = 0; i < 32; ++i) {
                const float4 kv = Kr[i];
                const float4 qv = qr[i];     // wave-uniform broadcast
                s += kv.x * qv.x + kv.y * qv.y + kv.z * qv.z + kv.w * qv.w;
            }
        }
        const int tok = p * T_ + t;
        if (tok >= len) s = -1e30f;

        // ---- online softmax update (per wave = per head) ----
        float smax = s;
#pragma unroll
        for (int off = 32; off; off >>= 1) smax = fmaxf(smax, __shfl_xor(smax, off));
        const float m_new = fmaxf(m_run, smax);
        const float pr    = __expf(s - m_new);        // masked lanes underflow to 0
        const float alpha = __expf(m_run - m_new);    // first page: exp(-inf) = 0
        float psum = pr;
#pragma unroll
        for (int off = 32; off; off >>= 1) psum += __shfl_xor(psum, off);
        l_run = alpha * l_run + psum;
        m_run = m_new;
        p_s[g * T_ + t] = pr;
        if (t == 0) alpha_s[g] = alpha;
        __syncthreads();

        // ---- PV accumulate: thread (dq, th), 8 tokens each, all 4 heads ----
        const float a0 = alpha_s[0], a1 = alpha_s[1], a2 = alpha_s[2], a3 = alpha_s[3];
        oacc[0].x *= a0; oacc[0].y *= a0; oacc[0].z *= a0; oacc[0].w *= a0;
        oacc[1].x *= a1; oacc[1].y *= a1; oacc[1].z *= a1; oacc[1].w *= a1;
        oacc[2].x *= a2; oacc[2].y *= a2; oacc[2].z *= a2; oacc[2].w *= a2;
        oacc[3].x *= a3; oacc[3].y *= a3; oacc[3].z *= a3; oacc[3].w *= a3;
#pragma unroll
        for (int tt = 0; tt < 8; ++tt) {
            const int t2 = th * 8 + tt;
            const float4 vv = V4[t2 * RS4 + dq];
            const float pv0 = p_s[0 * T_ + t2];
            const float pv1 = p_s[1 * T_ + t2];
            const float pv2 = p_s[2 * T_ + t2];
            const float pv3 = p_s[3 * T_ + t2];
            oacc[0].x += pv0 * vv.x; oacc[0].y += pv0 * vv.y; oacc[0].z += pv0 * vv.z; oacc[0].w += pv0 * vv.w;
            oacc[1].x += pv1 * vv.x; oacc[1].y += pv1 * vv.y; oacc[1].z += pv1 * vv.z; oacc[1].w += pv1 * vv.w;
            oacc[2].x += pv2 * vv.x; oacc[2].y += pv2 * vv.y; oacc[2].z += pv2 * vv.z; oacc[2].w += pv2 * vv.w;
            oacc[3].x += pv3 * vv.x; oacc[3].y += pv3 * vv.y; oacc[3].z += pv3 * vv.z; oacc[3].w += pv3 * vv.w;
        }
        __syncthreads();   // before next page overwrites K4/V4/p_s
    }

    // ---- combine the 8 token-octet partials (reuse K4 as scratch) ----
    float4* red = K4;
#pragma unroll
    for (int g2 = 0; g2 < G_; ++g2) red[(th * G_ + g2) * 32 + dq] = oacc[g2];
    if (t == 0) { m_part[bx * G_ + g] = m_run; l_part[bx * G_ + g] = l_run; }
    __syncthreads();

    if (tid < 128) {
        const int gg = tid >> 5;
        const int dd = tid & 31;
        float4 sum; sum.x = 0.f; sum.y = 0.f; sum.z = 0.f; sum.w = 0.f;
#pragma unroll
        for (int th2 = 0; th2 < 8; ++th2) {
            const float4 v = red[(th2 * G_ + gg) * 32 + dd];
            sum.x += v.x; sum.y += v.y; sum.z += v.z; sum.w += v.w;
        }
        float4* op = (float4*)(o_part + (size_t)bx * (G_ * D_));
        op[gg * 32 + dd] = sum;
    }
}

// ---------------- Kernel 2: combine chunk partials ----------------
__global__ __launch_bounds__(128)
void pa_reduce(const float* __restrict__ o_part,
               const float* __restrict__ m_part,
               const float* __restrict__ l_part,
               const int*   __restrict__ lengths,
               float* __restrict__ out)
{
    const int bx = blockIdx.x;          // (b, k, g)
    const int gg = bx & 3;
    const int k  = (bx >> 2) & 7;
    const int b  = bx >> 5;
    const int len = lengths[b];
    const int nc  = (len + 511) >> 9;   // valid chunks, 1..8
    const int base = (b * KVH_ + k) * NCHUNK;

    float M = -INFINITY;
#pragma unroll
    for (int c = 0; c < NCHUNK; ++c)
        if (c < nc) M = fmaxf(M, m_part[(base + c) * G_ + gg]);

    const int d = threadIdx.x;
    float L = 0.f;
    float acc = 0.f;
#pragma unroll
    for (int c = 0; c < NCHUNK; ++c) {
        if (c < nc) {
            const float wc = __expf(m_part[(base + c) * G_ + gg] - M);
            L   += wc * l_part[(base + c) * G_ + gg];
            acc += wc * o_part[(size_t)(base + c) * (G_ * D_) + gg * D_ + d];
        }
    }
    out[((size_t)b * H_ + (size_t)k * G_ + gg) * D_ + d] = acc / L;
}

extern "C" void kernel_launch(void* const* d_in, const int* in_sizes, int n_in,
                              void* d_out, int out_size, void* d_ws, size_t ws_size,
                              hipStream_t stream) {
    const float* q            = (const float*)d_in[0];
    const float* k_pages      = (const float*)d_in[1];
    const float* v_pages      = (const float*)d_in[2];
    const int*   lengths      = (const int*)d_in[3];
    const int*   page_indices = (const int*)d_in[4];
    float* out = (float*)d_out;

    float* o_part = (float*)d_ws;                                  // 2048*512 floats = 4 MiB
    float* m_part = o_part + (size_t)2048 * (G_ * D_);             // 8192 floats
    float* l_part = m_part + (size_t)2048 * G_;                    // 8192 floats

    pa_partial<<<B_ * KVH_ * NCHUNK, 256, 0, stream>>>(
        q, k_pages, v_pages, lengths, page_indices, o_part, m_part, l_part);
    pa_reduce<<<B_ * KVH_ * G_, 128, 0, stream>>>(
        o_part, m_part, l_part, lengths, out);
}